// Round 2
// baseline (121.879 us; speedup 1.0000x reference)
//
#include <hip/hip_runtime.h>

// TT Q-gather v3 — middle stages in LDS, global tables back to 2 MB.
//
//   v = V01[s0][s1][:]        (1 MB global table, L2-resident)
//   for k=2..5: v = v @ Gk[:,sk,:]   (bf16, from 128 KB LDS-staged tables)
//   q = v . U67[s6][a7][:]    (1 MB global table, L2-resident)
//
// Rationale (R1 post-mortem): gather time is insensitive to global
// divergent-load count (59 -> 34 -> 18 instrs, totals flat). Either the
// global divergent path is per-address bound regardless of count/locality
// tradeoffs, or we're at the harness floor (45us ws-poison fill). This
// version removes 32 of 34 divergent global loads: stage tables live in
// LDS ([r][n][s] layout so ds_read_b128 bank-group = 4n mod 32 spreads
// random n across all 8 groups; n-major layout would be 16-way conflict).
// 1024-thr blocks, 128 KB LDS, linear coalesced stage copy.
// If total is unchanged, the floor theory is confirmed.
//
// ws layout (ushort units):
//   V01 @ 0       : [s0][s1][s] 256*256*8   (1 MB)
//   U67 @ 524288  : [s6][a7][r] 256*256*8   (1 MB)
//   Gt  @ 1048576 : [k][r][n][s] 4*8*256*8  (256 KB) -- LDS image, r-major

#define NN 256
#define RR 8
#define NR 2048   // N * R
#define U67_OFF 524288
#define GT_OFF  1048576
#define GT_CORE 16384   // ushorts per core (32 KB)

__device__ __forceinline__ unsigned short f2bf_rne(float f) {
    unsigned int u = __float_as_uint(f);
    u += 0x7FFFu + ((u >> 16) & 1u);
    return (unsigned short)(u >> 16);
}

__device__ __forceinline__ uint4 pack8bf(const float* a) {
    return make_uint4(
        f2bf_rne(a[0]) | ((unsigned int)f2bf_rne(a[1]) << 16),
        f2bf_rne(a[2]) | ((unsigned int)f2bf_rne(a[3]) << 16),
        f2bf_rne(a[4]) | ((unsigned int)f2bf_rne(a[5]) << 16),
        f2bf_rne(a[6]) | ((unsigned int)f2bf_rne(a[7]) << 16));
}

// 544 blocks x 256 threads:
//   0..255   -> V01 row n0
//   256..511 -> U67 row n6
//   512..543 -> transpose G2..G5 into r-major LDS image (8 blocks/core)
__global__ __launch_bounds__(256) void build_tables(
    const float* __restrict__ G0, const float* __restrict__ G1,
    const float* __restrict__ G2, const float* __restrict__ G3,
    const float* __restrict__ G4, const float* __restrict__ G5,
    const float* __restrict__ G6, const float* __restrict__ G7,
    unsigned short* __restrict__ wsb) {
    const int t = threadIdx.x;
    const int bid = blockIdx.x;

    if (bid < NN) {
        // V01[n0][n1][s] = sum_r G0[n0,r] * G1[r,n1,s]
        const int n0 = bid, n1 = t;
        float acc[RR] = {0.f,0.f,0.f,0.f,0.f,0.f,0.f,0.f};
#pragma unroll
        for (int r = 0; r < RR; ++r) {
            float ar = G0[n0 * RR + r];
            const float4* p = (const float4*)(G1 + r * NR + n1 * RR);
            float4 x = p[0], y = p[1];
            acc[0] += ar * x.x; acc[1] += ar * x.y;
            acc[2] += ar * x.z; acc[3] += ar * x.w;
            acc[4] += ar * y.x; acc[5] += ar * y.y;
            acc[6] += ar * y.z; acc[7] += ar * y.w;
        }
        *(uint4*)(wsb + n0 * 2048 + n1 * 8) = pack8bf(acc);
    } else if (bid < 2 * NN) {
        // U67[n6][n7][r] = sum_s G6[r,n6,s] * G7[s,n7]
        const int n6 = bid - NN, n7 = t;
        float g7v[RR];
#pragma unroll
        for (int s = 0; s < RR; ++s) g7v[s] = G7[s * NN + n7];
        float u[RR];
#pragma unroll
        for (int r = 0; r < RR; ++r) {
            float acc = 0.f;
#pragma unroll
            for (int s = 0; s < RR; ++s)
                acc += G6[r * NR + n6 * RR + s] * g7v[s];
            u[r] = acc;
        }
        *(uint4*)(wsb + U67_OFF + n6 * 2048 + n7 * 8) = pack8bf(u);
    } else {
        // transpose G2..G5 -> Gt[k][r][n][s] bf16 (r-major LDS image)
        const int q = bid - 2 * NN;        // 0..31
        const int k = q >> 3;              // 0..3 -> G2..G5
        const int chunk = q & 7;
        const float* __restrict__ Gk =
            (k == 0) ? G2 : (k == 1) ? G3 : (k == 2) ? G4 : G5;
        const int n = chunk * 32 + (t >> 3);
        const int r = t & 7;
        const float4* src = (const float4*)(Gk + r * NR + n * RR);
        float4 x = src[0], y = src[1];
        float a[8] = {x.x, x.y, x.z, x.w, y.x, y.y, y.z, y.w};
        *(uint4*)(wsb + GT_OFF + k * GT_CORE + r * 2048 + n * 8) = pack8bf(a);
    }
}

#define BF2F_LO(u) __uint_as_float((u) << 16)
#define BF2F_HI(u) __uint_as_float((u) & 0xFFFF0000u)

// one chain stage from LDS: v = v @ Gk[:,nidx,:]
// rows r=0..7 live at uint4 index k*2048 + r*256 + nidx
#define LSTAGE(k, nidx)                                                     \
    do {                                                                    \
        const uint4* mp = l4 + (k) * 2048 + (nidx);                         \
        uint4 r0 = mp[0],    r1 = mp[256],  r2 = mp[512],  r3 = mp[768];    \
        uint4 r4 = mp[1024], r5 = mp[1280], r6 = mp[1536], r7 = mp[1792];   \
        float nv0, nv1, nv2, nv3, nv4, nv5, nv6, nv7;                       \
        nv0  = v[0] * BF2F_LO(r0.x); nv1  = v[0] * BF2F_HI(r0.x);           \
        nv2  = v[0] * BF2F_LO(r0.y); nv3  = v[0] * BF2F_HI(r0.y);           \
        nv4  = v[0] * BF2F_LO(r0.z); nv5  = v[0] * BF2F_HI(r0.z);           \
        nv6  = v[0] * BF2F_LO(r0.w); nv7  = v[0] * BF2F_HI(r0.w);           \
        nv0 += v[1] * BF2F_LO(r1.x); nv1 += v[1] * BF2F_HI(r1.x);           \
        nv2 += v[1] * BF2F_LO(r1.y); nv3 += v[1] * BF2F_HI(r1.y);           \
        nv4 += v[1] * BF2F_LO(r1.z); nv5 += v[1] * BF2F_HI(r1.z);           \
        nv6 += v[1] * BF2F_LO(r1.w); nv7 += v[1] * BF2F_HI(r1.w);           \
        nv0 += v[2] * BF2F_LO(r2.x); nv1 += v[2] * BF2F_HI(r2.x);           \
        nv2 += v[2] * BF2F_LO(r2.y); nv3 += v[2] * BF2F_HI(r2.y);           \
        nv4 += v[2] * BF2F_LO(r2.z); nv5 += v[2] * BF2F_HI(r2.z);           \
        nv6 += v[2] * BF2F_LO(r2.w); nv7 += v[2] * BF2F_HI(r2.w);           \
        nv0 += v[3] * BF2F_LO(r3.x); nv1 += v[3] * BF2F_HI(r3.x);           \
        nv2 += v[3] * BF2F_LO(r3.y); nv3 += v[3] * BF2F_HI(r3.y);           \
        nv4 += v[3] * BF2F_LO(r3.z); nv5 += v[3] * BF2F_HI(r3.z);           \
        nv6 += v[3] * BF2F_LO(r3.w); nv7 += v[3] * BF2F_HI(r3.w);           \
        nv0 += v[4] * BF2F_LO(r4.x); nv1 += v[4] * BF2F_HI(r4.x);           \
        nv2 += v[4] * BF2F_LO(r4.y); nv3 += v[4] * BF2F_HI(r4.y);           \
        nv4 += v[4] * BF2F_LO(r4.z); nv5 += v[4] * BF2F_HI(r4.z);           \
        nv6 += v[4] * BF2F_LO(r4.w); nv7 += v[4] * BF2F_HI(r4.w);           \
        nv0 += v[5] * BF2F_LO(r5.x); nv1 += v[5] * BF2F_HI(r5.x);           \
        nv2 += v[5] * BF2F_LO(r5.y); nv3 += v[5] * BF2F_HI(r5.y);           \
        nv4 += v[5] * BF2F_LO(r5.z); nv5 += v[5] * BF2F_HI(r5.z);           \
        nv6 += v[5] * BF2F_LO(r5.w); nv7 += v[5] * BF2F_HI(r5.w);           \
        nv0 += v[6] * BF2F_LO(r6.x); nv1 += v[6] * BF2F_HI(r6.x);           \
        nv2 += v[6] * BF2F_LO(r6.y); nv3 += v[6] * BF2F_HI(r6.y);           \
        nv4 += v[6] * BF2F_LO(r6.z); nv5 += v[6] * BF2F_HI(r6.z);           \
        nv6 += v[6] * BF2F_LO(r6.w); nv7 += v[6] * BF2F_HI(r6.w);           \
        nv0 += v[7] * BF2F_LO(r7.x); nv1 += v[7] * BF2F_HI(r7.x);           \
        nv2 += v[7] * BF2F_LO(r7.y); nv3 += v[7] * BF2F_HI(r7.y);           \
        nv4 += v[7] * BF2F_LO(r7.z); nv5 += v[7] * BF2F_HI(r7.z);           \
        nv6 += v[7] * BF2F_LO(r7.w); nv7 += v[7] * BF2F_HI(r7.w);           \
        v[0] = nv0; v[1] = nv1; v[2] = nv2; v[3] = nv3;                     \
        v[4] = nv4; v[5] = nv5; v[6] = nv6; v[7] = nv7;                     \
    } while (0)

__global__ __launch_bounds__(1024) void tt_gather(
    const unsigned short* __restrict__ wsb,
    const int* __restrict__ states, const int* __restrict__ actions,
    float* __restrict__ out, int B) {
    __shared__ unsigned short lut[4 * GT_CORE];   // 128 KB

    const int t = threadIdx.x;

    // linear coalesced stage: 128 KB = 8192 uint4, 8 per thread
    {
        const uint4* src = (const uint4*)(wsb + GT_OFF);
        uint4* dst = (uint4*)lut;
#pragma unroll
        for (int i = 0; i < 8; ++i) dst[t + (i << 10)] = src[t + (i << 10)];
    }
    __syncthreads();

    const int b = blockIdx.x * 1024 + t;
    const bool active = (b < B);
    const int base = active ? b * 7 : 0;
    const int s0 = states[base + 0] & 255;
    const int s1 = states[base + 1] & 255;
    const int s2 = states[base + 2] & 255;
    const int s3 = states[base + 3] & 255;
    const int s4 = states[base + 4] & 255;
    const int s5 = states[base + 5] & 255;
    const int s6 = states[base + 6] & 255;
    const int a7 = actions[active ? b : 0] & 255;

    // two remaining divergent global loads, both index-derived: issue early
    const uint4 uv = *(const uint4*)(wsb + s0 * 2048 + s1 * 8);
    const uint4 ue = *(const uint4*)(wsb + U67_OFF + s6 * 2048 + a7 * 8);

    float v[8];
    v[0] = BF2F_LO(uv.x); v[1] = BF2F_HI(uv.x);
    v[2] = BF2F_LO(uv.y); v[3] = BF2F_HI(uv.y);
    v[4] = BF2F_LO(uv.z); v[5] = BF2F_HI(uv.z);
    v[6] = BF2F_LO(uv.w); v[7] = BF2F_HI(uv.w);

    const uint4* l4 = (const uint4*)lut;
    LSTAGE(0, s2);
    LSTAGE(1, s3);
    LSTAGE(2, s4);
    LSTAGE(3, s5);

    float q = v[0] * BF2F_LO(ue.x) + v[1] * BF2F_HI(ue.x)
            + v[2] * BF2F_LO(ue.y) + v[3] * BF2F_HI(ue.y)
            + v[4] * BF2F_LO(ue.z) + v[5] * BF2F_HI(ue.z)
            + v[6] * BF2F_LO(ue.w) + v[7] * BF2F_HI(ue.w);
    if (active) out[b] = q;
}

extern "C" void kernel_launch(void* const* d_in, const int* in_sizes, int n_in,
                              void* d_out, int out_size, void* d_ws, size_t ws_size,
                              hipStream_t stream) {
    const float* G0 = (const float*)d_in[0];
    const float* G1 = (const float*)d_in[1];
    const float* G2 = (const float*)d_in[2];
    const float* G3 = (const float*)d_in[3];
    const float* G4 = (const float*)d_in[4];
    const float* G5 = (const float*)d_in[5];
    const float* G6 = (const float*)d_in[6];
    const float* G7 = (const float*)d_in[7];
    const int* states  = (const int*)d_in[8];
    const int* actions = (const int*)d_in[9];
    float* out = (float*)d_out;
    int B = in_sizes[9];

    unsigned short* wsb = (unsigned short*)d_ws;   // ~2.25 MB used

    hipLaunchKernelGGL(build_tables, dim3(2 * NN + 32), dim3(256), 0, stream,
                       G0, G1, G2, G3, G4, G5, G6, G7, wsb);

    hipLaunchKernelGGL(tt_gather, dim3((B + 1023) / 1024), dim3(1024), 0, stream,
                       wsb, states, actions, out, B);
}

// Round 3
// 89.747 us; speedup vs baseline: 1.3580x; 1.3580x over previous
//
#include <hip/hip_runtime.h>

// TT Q-gather v4 — v3 with the spill fixed: 512-thread blocks.
//
//   v = V01[s0][s1][:]        (1 MB global table, L2-resident)
//   for k=2..5: v = v @ Gk[:,sk,:]   (bf16, from 128 KB LDS-staged tables)
//   q = v . U67[s6][a7][:]    (1 MB global table, L2-resident)
//
// R2 post-mortem: 1024-thr blocks -> compiler capped at 64 VGPR -> the
// 8x uint4 row arrays spilled to scratch. 171 MB of scratch traffic at
// 3.15 TB/s = the measured 54.2us (VALUBusy 0.06%). Fix: 512 threads,
// __launch_bounds__(512,2) -> 256-VGPR budget (~90 needed), LDS 128 KB
// still 1 block/CU, 8 waves. Predicted gather ~7us (2us VALU + 2.6us LDS
// + 2us stage), WRITE_SIZE back to ~1 MB, FETCH ~12 MB.
//
// ws layout (ushort units):
//   V01 @ 0       : [s0][s1][s] 256*256*8   (1 MB)
//   U67 @ 524288  : [s6][a7][r] 256*256*8   (1 MB)
//   Gt  @ 1048576 : [k][r][n][s] 4*8*256*8  (256 KB) -- LDS image, r-major

#define NN 256
#define RR 8
#define NR 2048   // N * R
#define U67_OFF 524288
#define GT_OFF  1048576
#define GT_CORE 16384   // ushorts per core (32 KB)

__device__ __forceinline__ unsigned short f2bf_rne(float f) {
    unsigned int u = __float_as_uint(f);
    u += 0x7FFFu + ((u >> 16) & 1u);
    return (unsigned short)(u >> 16);
}

__device__ __forceinline__ uint4 pack8bf(const float* a) {
    return make_uint4(
        f2bf_rne(a[0]) | ((unsigned int)f2bf_rne(a[1]) << 16),
        f2bf_rne(a[2]) | ((unsigned int)f2bf_rne(a[3]) << 16),
        f2bf_rne(a[4]) | ((unsigned int)f2bf_rne(a[5]) << 16),
        f2bf_rne(a[6]) | ((unsigned int)f2bf_rne(a[7]) << 16));
}

// 544 blocks x 256 threads:
//   0..255   -> V01 row n0
//   256..511 -> U67 row n6
//   512..543 -> transpose G2..G5 into r-major image (8 blocks/core)
__global__ __launch_bounds__(256) void build_tables(
    const float* __restrict__ G0, const float* __restrict__ G1,
    const float* __restrict__ G2, const float* __restrict__ G3,
    const float* __restrict__ G4, const float* __restrict__ G5,
    const float* __restrict__ G6, const float* __restrict__ G7,
    unsigned short* __restrict__ wsb) {
    const int t = threadIdx.x;
    const int bid = blockIdx.x;

    if (bid < NN) {
        // V01[n0][n1][s] = sum_r G0[n0,r] * G1[r,n1,s]
        const int n0 = bid, n1 = t;
        float acc[RR] = {0.f,0.f,0.f,0.f,0.f,0.f,0.f,0.f};
#pragma unroll
        for (int r = 0; r < RR; ++r) {
            float ar = G0[n0 * RR + r];
            const float4* p = (const float4*)(G1 + r * NR + n1 * RR);
            float4 x = p[0], y = p[1];
            acc[0] += ar * x.x; acc[1] += ar * x.y;
            acc[2] += ar * x.z; acc[3] += ar * x.w;
            acc[4] += ar * y.x; acc[5] += ar * y.y;
            acc[6] += ar * y.z; acc[7] += ar * y.w;
        }
        *(uint4*)(wsb + n0 * 2048 + n1 * 8) = pack8bf(acc);
    } else if (bid < 2 * NN) {
        // U67[n6][n7][r] = sum_s G6[r,n6,s] * G7[s,n7]
        const int n6 = bid - NN, n7 = t;
        float g7v[RR];
#pragma unroll
        for (int s = 0; s < RR; ++s) g7v[s] = G7[s * NN + n7];
        float u[RR];
#pragma unroll
        for (int r = 0; r < RR; ++r) {
            float acc = 0.f;
#pragma unroll
            for (int s = 0; s < RR; ++s)
                acc += G6[r * NR + n6 * RR + s] * g7v[s];
            u[r] = acc;
        }
        *(uint4*)(wsb + U67_OFF + n6 * 2048 + n7 * 8) = pack8bf(u);
    } else {
        // transpose G2..G5 -> Gt[k][r][n][s] bf16 (r-major LDS image)
        const int q = bid - 2 * NN;        // 0..31
        const int k = q >> 3;              // 0..3 -> G2..G5
        const int chunk = q & 7;
        const float* __restrict__ Gk =
            (k == 0) ? G2 : (k == 1) ? G3 : (k == 2) ? G4 : G5;
        const int n = chunk * 32 + (t >> 3);
        const int r = t & 7;
        const float4* src = (const float4*)(Gk + r * NR + n * RR);
        float4 x = src[0], y = src[1];
        float a[8] = {x.x, x.y, x.z, x.w, y.x, y.y, y.z, y.w};
        *(uint4*)(wsb + GT_OFF + k * GT_CORE + r * 2048 + n * 8) = pack8bf(a);
    }
}

#define BF2F_LO(u) __uint_as_float((u) << 16)
#define BF2F_HI(u) __uint_as_float((u) & 0xFFFF0000u)

// one chain stage from LDS: v = v @ Gk[:,nidx,:]
// rows r=0..7 live at uint4 index k*2048 + r*256 + nidx
#define LSTAGE(k, nidx)                                                     \
    do {                                                                    \
        const uint4* mp = l4 + (k) * 2048 + (nidx);                         \
        uint4 r0 = mp[0],    r1 = mp[256],  r2 = mp[512],  r3 = mp[768];    \
        uint4 r4 = mp[1024], r5 = mp[1280], r6 = mp[1536], r7 = mp[1792];   \
        float nv0, nv1, nv2, nv3, nv4, nv5, nv6, nv7;                       \
        nv0  = v[0] * BF2F_LO(r0.x); nv1  = v[0] * BF2F_HI(r0.x);           \
        nv2  = v[0] * BF2F_LO(r0.y); nv3  = v[0] * BF2F_HI(r0.y);           \
        nv4  = v[0] * BF2F_LO(r0.z); nv5  = v[0] * BF2F_HI(r0.z);           \
        nv6  = v[0] * BF2F_LO(r0.w); nv7  = v[0] * BF2F_HI(r0.w);           \
        nv0 += v[1] * BF2F_LO(r1.x); nv1 += v[1] * BF2F_HI(r1.x);           \
        nv2 += v[1] * BF2F_LO(r1.y); nv3 += v[1] * BF2F_HI(r1.y);           \
        nv4 += v[1] * BF2F_LO(r1.z); nv5 += v[1] * BF2F_HI(r1.z);           \
        nv6 += v[1] * BF2F_LO(r1.w); nv7 += v[1] * BF2F_HI(r1.w);           \
        nv0 += v[2] * BF2F_LO(r2.x); nv1 += v[2] * BF2F_HI(r2.x);           \
        nv2 += v[2] * BF2F_LO(r2.y); nv3 += v[2] * BF2F_HI(r2.y);           \
        nv4 += v[2] * BF2F_LO(r2.z); nv5 += v[2] * BF2F_HI(r2.z);           \
        nv6 += v[2] * BF2F_LO(r2.w); nv7 += v[2] * BF2F_HI(r2.w);           \
        nv0 += v[3] * BF2F_LO(r3.x); nv1 += v[3] * BF2F_HI(r3.x);           \
        nv2 += v[3] * BF2F_LO(r3.y); nv3 += v[3] * BF2F_HI(r3.y);           \
        nv4 += v[3] * BF2F_LO(r3.z); nv5 += v[3] * BF2F_HI(r3.z);           \
        nv6 += v[3] * BF2F_LO(r3.w); nv7 += v[3] * BF2F_HI(r3.w);           \
        nv0 += v[4] * BF2F_LO(r4.x); nv1 += v[4] * BF2F_HI(r4.x);           \
        nv2 += v[4] * BF2F_LO(r4.y); nv3 += v[4] * BF2F_HI(r4.y);           \
        nv4 += v[4] * BF2F_LO(r4.z); nv5 += v[4] * BF2F_HI(r4.z);           \
        nv6 += v[4] * BF2F_LO(r4.w); nv7 += v[4] * BF2F_HI(r4.w);           \
        nv0 += v[5] * BF2F_LO(r5.x); nv1 += v[5] * BF2F_HI(r5.x);           \
        nv2 += v[5] * BF2F_LO(r5.y); nv3 += v[5] * BF2F_HI(r5.y);           \
        nv4 += v[5] * BF2F_LO(r5.z); nv5 += v[5] * BF2F_HI(r5.z);           \
        nv6 += v[5] * BF2F_LO(r5.w); nv7 += v[5] * BF2F_HI(r5.w);           \
        nv0 += v[6] * BF2F_LO(r6.x); nv1 += v[6] * BF2F_HI(r6.x);           \
        nv2 += v[6] * BF2F_LO(r6.y); nv3 += v[6] * BF2F_HI(r6.y);           \
        nv4 += v[6] * BF2F_LO(r6.z); nv5 += v[6] * BF2F_HI(r6.z);           \
        nv6 += v[6] * BF2F_LO(r6.w); nv7 += v[6] * BF2F_HI(r6.w);           \
        nv0 += v[7] * BF2F_LO(r7.x); nv1 += v[7] * BF2F_HI(r7.x);           \
        nv2 += v[7] * BF2F_LO(r7.y); nv3 += v[7] * BF2F_HI(r7.y);           \
        nv4 += v[7] * BF2F_LO(r7.z); nv5 += v[7] * BF2F_HI(r7.z);           \
        nv6 += v[7] * BF2F_LO(r7.w); nv7 += v[7] * BF2F_HI(r7.w);           \
        v[0] = nv0; v[1] = nv1; v[2] = nv2; v[3] = nv3;                     \
        v[4] = nv4; v[5] = nv5; v[6] = nv6; v[7] = nv7;                     \
    } while (0)

__global__ __launch_bounds__(512, 2) void tt_gather(
    const unsigned short* __restrict__ wsb,
    const int* __restrict__ states, const int* __restrict__ actions,
    float* __restrict__ out, int B) {
    __shared__ unsigned short lut[4 * GT_CORE];   // 128 KB

    const int t = threadIdx.x;

    // linear coalesced stage: 128 KB = 8192 uint4, 16 per thread
    {
        const uint4* src = (const uint4*)(wsb + GT_OFF);
        uint4* dst = (uint4*)lut;
#pragma unroll
        for (int i = 0; i < 16; ++i) dst[t + (i << 9)] = src[t + (i << 9)];
    }
    __syncthreads();

    const int b = blockIdx.x * 512 + t;
    const bool active = (b < B);
    const int base = active ? b * 7 : 0;
    const int s0 = states[base + 0] & 255;
    const int s1 = states[base + 1] & 255;
    const int s2 = states[base + 2] & 255;
    const int s3 = states[base + 3] & 255;
    const int s4 = states[base + 4] & 255;
    const int s5 = states[base + 5] & 255;
    const int s6 = states[base + 6] & 255;
    const int a7 = actions[active ? b : 0] & 255;

    // two remaining divergent global loads, both index-derived: issue early
    const uint4 uv = *(const uint4*)(wsb + s0 * 2048 + s1 * 8);
    const uint4 ue = *(const uint4*)(wsb + U67_OFF + s6 * 2048 + a7 * 8);

    float v[8];
    v[0] = BF2F_LO(uv.x); v[1] = BF2F_HI(uv.x);
    v[2] = BF2F_LO(uv.y); v[3] = BF2F_HI(uv.y);
    v[4] = BF2F_LO(uv.z); v[5] = BF2F_HI(uv.z);
    v[6] = BF2F_LO(uv.w); v[7] = BF2F_HI(uv.w);

    const uint4* l4 = (const uint4*)lut;
    LSTAGE(0, s2);
    LSTAGE(1, s3);
    LSTAGE(2, s4);
    LSTAGE(3, s5);

    float q = v[0] * BF2F_LO(ue.x) + v[1] * BF2F_HI(ue.x)
            + v[2] * BF2F_LO(ue.y) + v[3] * BF2F_HI(ue.y)
            + v[4] * BF2F_LO(ue.z) + v[5] * BF2F_HI(ue.z)
            + v[6] * BF2F_LO(ue.w) + v[7] * BF2F_HI(ue.w);
    if (active) out[b] = q;
}

extern "C" void kernel_launch(void* const* d_in, const int* in_sizes, int n_in,
                              void* d_out, int out_size, void* d_ws, size_t ws_size,
                              hipStream_t stream) {
    const float* G0 = (const float*)d_in[0];
    const float* G1 = (const float*)d_in[1];
    const float* G2 = (const float*)d_in[2];
    const float* G3 = (const float*)d_in[3];
    const float* G4 = (const float*)d_in[4];
    const float* G5 = (const float*)d_in[5];
    const float* G6 = (const float*)d_in[6];
    const float* G7 = (const float*)d_in[7];
    const int* states  = (const int*)d_in[8];
    const int* actions = (const int*)d_in[9];
    float* out = (float*)d_out;
    int B = in_sizes[9];

    unsigned short* wsb = (unsigned short*)d_ws;   // ~2.25 MB used

    hipLaunchKernelGGL(build_tables, dim3(2 * NN + 32), dim3(256), 0, stream,
                       G0, G1, G2, G3, G4, G5, G6, G7, wsb);

    hipLaunchKernelGGL(tt_gather, dim3((B + 511) / 512), dim3(512), 0, stream,
                       wsb, states, actions, out, B);
}